// Round 1
// baseline (734.175 us; speedup 1.0000x reference)
//
#include <hip/hip_runtime.h>

#define B_   8
#define C_   512
#define HW_  2304
#define BM   128
#define BN   128
#define BKQ  32              // K-step (elements); row = 64 B
#define NKS  (C_ / BKQ)      // 16
#define NT_  (HW_ / BN)      // 18
#define MT_PER_BLOCK 3
#define MCHUNKS 6            // 18 m-tiles / 3

typedef __bf16 bf16x8 __attribute__((ext_vector_type(8)));
typedef float  f32x4  __attribute__((ext_vector_type(4)));

__device__ __forceinline__ unsigned short f2bf(float f) {
  unsigned int u = __float_as_uint(f);
  u += 0x7FFF + ((u >> 16) & 1);   // round-to-nearest-even
  return (unsigned short)(u >> 16);
}

__device__ __forceinline__ void gload_lds16(const void* g, void* l) {
  __builtin_amdgcn_global_load_lds(
      (const __attribute__((address_space(1))) unsigned int*)g,
      (__attribute__((address_space(3))) unsigned int*)l, 16, 0, 0);
}

__global__ void zero_out(float* __restrict__ out, int n) {
  int i = blockIdx.x * 256 + threadIdx.x;
  if (i < n) out[i] = 0.0f;
}

// Fused: key fp32 [b][c][n] -> keyT bf16 [b][n][c], plus coarse partial dots
// (fp32, atomicAdd into pre-zeroed out channels 4..9).
__global__ void transpose_coarse(const float* __restrict__ key,
                                 const float* __restrict__ v0, const float* __restrict__ v1,
                                 const float* __restrict__ v2, const float* __restrict__ v3,
                                 const float* __restrict__ v4, const float* __restrict__ v5,
                                 unsigned short* __restrict__ keyT,
                                 float* __restrict__ out) {
  __shared__ float tile[32][33];
  __shared__ float red2[6][8][32];
  int b  = blockIdx.z;
  int n0 = blockIdx.x * 32;
  int c0 = blockIdx.y * 32;
  int tx = threadIdx.x;  // 0..31
  int ty = threadIdx.y;  // 0..7
#pragma unroll
  for (int i = 0; i < 4; i++) {
    int c = c0 + ty + i * 8;
    tile[ty + i * 8][tx] = key[(size_t)b * C_ * HW_ + (size_t)c * HW_ + n0 + tx];
  }
  __syncthreads();
#pragma unroll
  for (int i = 0; i < 4; i++) {
    int n = n0 + ty + i * 8;
    keyT[(size_t)b * HW_ * C_ + (size_t)n * C_ + c0 + tx] = f2bf(tile[tx][ty + i * 8]);
  }
  // coarse partials: thread covers n = n0+tx, c-range = c0 + ty*4 .. +4
  float s[6] = {0.f, 0.f, 0.f, 0.f, 0.f, 0.f};
#pragma unroll
  for (int i = 0; i < 4; i++) {
    int cr = ty * 4 + i;
    int c  = c0 + cr;
    float kv = tile[cr][tx];
    s[0] += v0[b * C_ + c] * kv;
    s[1] += v1[b * C_ + c] * kv;
    s[2] += v2[b * C_ + c] * kv;
    s[3] += v3[b * C_ + c] * kv;
    s[4] += v4[b * C_ + c] * kv;
    s[5] += v5[b * C_ + c] * kv;
  }
#pragma unroll
  for (int j = 0; j < 6; j++) red2[j][ty][tx] = s[j];
  __syncthreads();
  if (ty < 6) {
    float a = 0.f;
#pragma unroll
    for (int k = 0; k < 8; k++) a += red2[ty][k][tx];
    atomicAdd(&out[((size_t)b * 10 + 4 + ty) * HW_ + n0 + tx], a);
  }
}

// 4 fine banks fp32 [b][m][c] -> bf16 stacked [g][b][m][c]
__global__ void convert_banks(const float* __restrict__ b0, const float* __restrict__ b1,
                              const float* __restrict__ b2, const float* __restrict__ b3,
                              unsigned short* __restrict__ out) {
  const size_t per = (size_t)B_ * HW_ * C_;
  int g = blockIdx.y;
  const float* src = (g == 0) ? b0 : (g == 1) ? b1 : (g == 2) ? b2 : b3;
  size_t i = ((size_t)blockIdx.x * blockDim.x + threadIdx.x) * 4;
  float4 v = *(const float4*)(src + i);
  ushort4 o;
  o.x = f2bf(v.x); o.y = f2bf(v.y); o.z = f2bf(v.z); o.w = f2bf(v.w);
  *(ushort4*)(out + g * per + i) = o;
}

// Fine scores, bank-paired: block handles banks {2gp, 2gp+1} (they share the
// B tile and, for gp==1, the mask) for 3 m-tiles of one (nt, b).
// XCD-pinned decode: b = lin & 7 -> each XCD owns one batch (keyT_b stays
// L2-resident); within the XCD, gp=0 slice then gp=1 slice, mc-major so the
// 18 nt-blocks sharing an A m-chunk run concurrently.
// K-loop: BK=32 double-buffered LDS, one barrier per K-step, prefetch of
// step k+1 (or next m-tile's step 0, covering the mask epilogue) issued
// before compute of step k.
__global__ __launch_bounds__(256, 3) void fine_kernel(
    const unsigned short* __restrict__ keyT,   // bf16 [b][n][c]
    const unsigned short* __restrict__ banks,  // bf16 [g][b][m][c]
    const float* __restrict__ sds,             // fp32 [b][m][n]
    float* __restrict__ pmax) {
  int lin = blockIdx.x;
  int b   = lin & 7;               // XCD-pinned batch
  int ix  = lin >> 3;              // 0..215
  int gp  = (ix >= 108) ? 1 : 0;   // 0: banks 0,1 (unmasked)  1: banks 2,3 (masked)
  int w   = ix - gp * 108;         // 0..107
  int mc  = w / NT_;               // 0..5  (mc-major for A reuse in L2)
  int nt  = w % NT_;
  int n0  = nt * BN;

  __shared__ __align__(16) unsigned short sbuf[2][3][BM * BKQ];  // 48 KB dbuf
  __shared__ float red[4 * BN];

  int t    = threadIdx.x;
  int wave = t >> 6;
  int lane = t & 63;
  int quad = lane >> 4;
  int l15  = lane & 15;
  int wm   = (wave & 1) * 64;
  int wn   = (wave >> 1) * 64;

  // staging: lane writes LDS row (rbase + lane>>2), 16B slot (lane&3).
  // source pre-swizzle so read slot = quad ^ ((row>>1)&3) returns chunk quad.
  int ksub = (lane & 3) ^ ((lane >> 3) & 3);   // global 8-elem chunk for this lane
  int swo  = (quad ^ ((l15 >> 1) & 3)) * 8;    // fragment-read element offset

  const unsigned short* bank0 = banks + ((size_t)(2 * gp) * B_ + b) * (size_t)HW_ * C_;
  const unsigned short* bank1 = banks + ((size_t)(2 * gp + 1) * B_ + b) * (size_t)HW_ * C_;
  const unsigned short* keyb  = keyT + (size_t)b * HW_ * C_;
  const float* maskb = sds + (size_t)b * HW_ * HW_;
  const bool masked = (gp == 1);

  auto STAGE = [&](int buf, int m0s, int kc) {
    unsigned short* A0d = &sbuf[buf][0][0];
    unsigned short* A1d = &sbuf[buf][1][0];
    unsigned short* Bd  = &sbuf[buf][2][0];
#pragma unroll
    for (int j = 0; j < 2; j++) {
      int rbase = j * 64 + wave * 16;                       // wave-uniform LDS row base
      size_t go = (size_t)(rbase + (lane >> 2)) * C_ + (size_t)kc * BKQ + ksub * 8;
      gload_lds16(bank0 + (size_t)m0s * C_ + go, &A0d[rbase * BKQ]);
      gload_lds16(bank1 + (size_t)m0s * C_ + go, &A1d[rbase * BKQ]);
      gload_lds16(keyb  + (size_t)n0  * C_ + go, &Bd [rbase * BKQ]);
    }
  };

  float rm0[4], rm1[4];
#pragma unroll
  for (int i = 0; i < 4; i++) { rm0[i] = -3.4e38f; rm1[i] = -3.4e38f; }

  int cur = 0;
  STAGE(0, mc * MT_PER_BLOCK * BM, 0);   // prologue

  for (int mi = 0; mi < MT_PER_BLOCK; mi++) {
    int m0 = (mc * MT_PER_BLOCK + mi) * BM;
    f32x4 acc0[4][4], acc1[4][4];
#pragma unroll
    for (int i = 0; i < 4; i++)
#pragma unroll
      for (int j = 0; j < 4; j++)
#pragma unroll
        for (int e = 0; e < 4; e++) { acc0[i][j][e] = 0.0f; acc1[i][j][e] = 0.0f; }

    for (int kc = 0; kc < NKS; kc++) {
      __syncthreads();   // drains prior prefetch (vmcnt) + prior frag reads
      if (kc + 1 < NKS)                STAGE(cur ^ 1, m0, kc + 1);
      else if (mi + 1 < MT_PER_BLOCK)  STAGE(cur ^ 1, m0 + BM, 0);

      const unsigned short* A0s = &sbuf[cur][0][0];
      const unsigned short* A1s = &sbuf[cur][1][0];
      const unsigned short* Bs  = &sbuf[cur][2][0];
      bf16x8 a0[4], a1[4], bb[4];
#pragma unroll
      for (int ms = 0; ms < 4; ms++) {
        a0[ms] = *(const bf16x8*)(&A0s[(wm + ms * 16 + l15) * BKQ + swo]);
        a1[ms] = *(const bf16x8*)(&A1s[(wm + ms * 16 + l15) * BKQ + swo]);
      }
#pragma unroll
      for (int ns = 0; ns < 4; ns++)
        bb[ns] = *(const bf16x8*)(&Bs[(wn + ns * 16 + l15) * BKQ + swo]);
#pragma unroll
      for (int ms = 0; ms < 4; ms++)
#pragma unroll
        for (int ns = 0; ns < 4; ns++) {
          acc0[ms][ns] = __builtin_amdgcn_mfma_f32_16x16x32_bf16(
              a0[ms], bb[ns], acc0[ms][ns], 0, 0, 0);
          acc1[ms][ns] = __builtin_amdgcn_mfma_f32_16x16x32_bf16(
              a1[ms], bb[ns], acc1[ms][ns], 0, 0, 0);
        }
      cur ^= 1;
    }

    // epilogue (registers + mask global loads only; next m-tile's first
    // K-step prefetch is in flight underneath)
    // lane holds S[m0+wm+ms*16+quad*4+r][n0+wn+ns*16+l15]
#pragma unroll
    for (int ms = 0; ms < 4; ms++) {
#pragma unroll
      for (int ns = 0; ns < 4; ns++) {
        int n = n0 + wn + ns * 16 + l15;
#pragma unroll
        for (int r = 0; r < 4; r++) {
          int m = m0 + wm + ms * 16 + quad * 4 + r;
          float s0 = acc0[ms][ns][r];
          float s1 = acc1[ms][ns][r];
          if (masked) {
            float w_ = maskb[(size_t)m * HW_ + n];   // one load, two uses
            s0 *= w_; s1 *= w_;
          }
          rm0[ns] = fmaxf(rm0[ns], s0);
          rm1[ns] = fmaxf(rm1[ns], s1);
        }
      }
    }
  }

  // reduce across quads (same column, different m rows)
#pragma unroll
  for (int ns = 0; ns < 4; ns++) {
    float v = rm0[ns];
    v = fmaxf(v, __shfl_xor(v, 16, 64));
    v = fmaxf(v, __shfl_xor(v, 32, 64));
    rm0[ns] = v;
    float u = rm1[ns];
    u = fmaxf(u, __shfl_xor(u, 16, 64));
    u = fmaxf(u, __shfl_xor(u, 32, 64));
    rm1[ns] = u;
  }
  if (lane < 16) {
#pragma unroll
    for (int ns = 0; ns < 4; ns++) {
      red[(wave & 1) * BN + wn + ns * 16 + l15]           = rm0[ns];
      red[2 * BN + (wave & 1) * BN + wn + ns * 16 + l15]  = rm1[ns];
    }
  }
  __syncthreads();
  if (t < BN) {
    float vv0 = fmaxf(red[t], red[BN + t]);
    float vv1 = fmaxf(red[2 * BN + t], red[3 * BN + t]);
    pmax[(((size_t)mc * B_ + b) * 4 + 2 * gp)     * HW_ + n0 + t] = vv0;
    pmax[(((size_t)mc * B_ + b) * 4 + 2 * gp + 1) * HW_ + n0 + t] = vv1;
  }
}

// max over m-chunks -> out channels 0..3
__global__ void fine_combine(const float* __restrict__ pmax, float* __restrict__ out) {
  int i = blockIdx.x * 256 + threadIdx.x;   // over B_*4*HW_
  if (i >= B_ * 4 * HW_) return;
  int n = i % HW_;
  int g = (i / HW_) % 4;
  int b = i / (HW_ * 4);
  float v = -3.4e38f;
#pragma unroll
  for (int mc = 0; mc < MCHUNKS; mc++)
    v = fmaxf(v, pmax[(((size_t)mc * B_ + b) * 4 + g) * HW_ + n]);
  out[((size_t)b * 10 + g) * HW_ + n] = v;
}

extern "C" void kernel_launch(void* const* d_in, const int* in_sizes, int n_in,
                              void* d_out, int out_size, void* d_ws, size_t ws_size,
                              hipStream_t stream) {
  const float* key  = (const float*)d_in[0];
  const float* sds  = (const float*)d_in[1];
  const float* gbg  = (const float*)d_in[2];
  const float* gfg  = (const float*)d_in[3];
  const float* lbg  = (const float*)d_in[4];
  const float* lfg  = (const float*)d_in[5];
  const float* obg  = (const float*)d_in[6];
  const float* ofg  = (const float*)d_in[7];
  const float* sbg  = (const float*)d_in[8];
  const float* sfg  = (const float*)d_in[9];
  const float* lobg = (const float*)d_in[10];
  const float* lofg = (const float*)d_in[11];
  float* out = (float*)d_out;

  unsigned short* keyT  = (unsigned short*)d_ws;               // 18.9 MB
  unsigned short* banks = keyT + (size_t)B_ * HW_ * C_;        // +75.5 MB
  float* pmax = (float*)(banks + (size_t)4 * B_ * HW_ * C_);   // +1.77 MB

  zero_out<<<(out_size + 255) / 256, 256, 0, stream>>>(out, out_size);
  convert_banks<<<dim3((B_ * HW_ * C_) / (4 * 256), 4), 256, 0, stream>>>(gbg, gfg, lbg, lfg, banks);
  transpose_coarse<<<dim3(HW_ / 32, C_ / 32, B_), dim3(32, 8), 0, stream>>>(
      key, obg, ofg, sbg, sfg, lobg, lofg, keyT, out);
  fine_kernel<<<dim3(NT_ * MCHUNKS * 2 * B_), 256, 0, stream>>>(keyT, banks, sds, pmax);
  fine_combine<<<(B_ * 4 * HW_ + 255) / 256, 256, 0, stream>>>(pmax, out);
}